// Round 3
// baseline (163.245 us; speedup 1.0000x reference)
//
#include <hip/hip_runtime.h>
#include <hip/hip_bf16.h>
#include <cstdint>

#define EPS 1e-5f
#define PATH_COEFF 0.04419417382415922f   // 1/sqrt(512)
#define CG110     0.5773502691896258f     // 1/sqrt(3)

typedef __bf16 v8bf __attribute__((ext_vector_type(8)));
typedef float  v4f  __attribute__((ext_vector_type(4)));

static __device__ __forceinline__ unsigned short f2bf(float x){
    unsigned int u = __builtin_bit_cast(unsigned int, x);
    u += 0x7fffu + ((u >> 16) & 1u);      // RNE
    return (unsigned short)(u >> 16);
}
static __device__ __forceinline__ unsigned short f2h(float x){
    return __builtin_bit_cast(unsigned short, (_Float16)x);
}
static __device__ __forceinline__ float h2f(unsigned short b){
    return (float)__builtin_bit_cast(_Float16, b);
}

// ---------------------------------------------------------------------------
// K0 mega-kernel: blocks [0,260) convert we_w2/we_b2 -> Vt2 frag-major,
// blocks [260,264) transpose om_w1 -> w1t bf16, blocks [264,272) per-row prep.
// Shared 64 KB LDS buffer reused by all three bodies.
// ---------------------------------------------------------------------------
__global__ __launch_bounds__(256)
void k_mega(const float* __restrict__ w2, const float* __restrict__ b2,
            unsigned short* __restrict__ Vt2,
            const float* __restrict__ om_w1, unsigned short* __restrict__ w1t,
            const float* __restrict__ x, const float* __restrict__ lng,
            const float* __restrict__ lnb, const float* __restrict__ we_w1,
            unsigned short* __restrict__ Q2, float* __restrict__ Ht, int N)
{
    __shared__ __align__(16) char smem[65536];
    int b = blockIdx.x;
    int t = threadIdx.x;

    if (b < 260){
        // ---- convV: Vt2[k][ps16][quad4][w128][8p] bf16 ----
        unsigned short (*tile)[128] = (unsigned short (*)[128])smem;
        int k    = b >> 2;
        int slab = b & 3;
        const float* srcbase = (k < 64) ? (w2 + (size_t)k * 65536) : b2;
        for (int chunk = 0; chunk < 4; ++chunk){
            int pbase = slab*128 + chunk*32;
            #pragma unroll
            for (int i = 0; i < 4; ++i){
                int g = t + 256*i;
                int ploc = g >> 5, c4 = g & 31;
                const float4 v = *(const float4*)(srcbase + (size_t)(pbase + ploc)*128 + c4*4);
                unsigned int w0 = (unsigned)f2bf(v.x) | ((unsigned)f2bf(v.y) << 16);
                unsigned int w1 = (unsigned)f2bf(v.z) | ((unsigned)f2bf(v.w) << 16);
                *(uint2*)&tile[ploc][c4*4] = make_uint2(w0, w1);
            }
            __syncthreads();
            int w = t & 127, h = t >> 7;
            int ps = slab*4 + chunk;
            unsigned int words[8];
            #pragma unroll
            for (int g2 = 0; g2 < 8; ++g2)
                words[g2] = (unsigned)tile[h*16 + g2*2][w] | ((unsigned)tile[h*16 + g2*2 + 1][w] << 16);
            unsigned short* dq0 = Vt2 + (((size_t)(k*16 + ps)*4 + 2*h    )*128 + w)*8;
            unsigned short* dq1 = Vt2 + (((size_t)(k*16 + ps)*4 + 2*h + 1)*128 + w)*8;
            *(uint4*)dq0 = make_uint4(words[0], words[1], words[2], words[3]);
            *(uint4*)dq1 = make_uint4(words[4], words[5], words[6], words[7]);
            __syncthreads();
        }
    } else if (b < 264){
        // ---- convW: w1t[j512][w128] bf16 = om_w1[w][j] ----
        unsigned short (*tile)[128] = (unsigned short (*)[128])smem;
        int j0 = (b - 260) * 128;
        for (int chunk = 0; chunk < 4; ++chunk){
            #pragma unroll
            for (int i = 0; i < 4; ++i){
                int g = t + 256*i;
                int wloc = g >> 5, c4 = g & 31;
                int w = chunk*32 + wloc;
                const float4 v = *(const float4*)(om_w1 + (size_t)w*512 + j0 + c4*4);
                unsigned int a = (unsigned)f2bf(v.x) | ((unsigned)f2bf(v.y) << 16);
                unsigned int bb = (unsigned)f2bf(v.z) | ((unsigned)f2bf(v.w) << 16);
                *(uint2*)&tile[wloc][c4*4] = make_uint2(a, bb);
            }
            __syncthreads();
            int jl = t & 127, h = t >> 7;
            unsigned int words[8];
            #pragma unroll
            for (int g2 = 0; g2 < 8; ++g2)
                words[g2] = (unsigned)tile[h*16 + g2*2][jl] | ((unsigned)tile[h*16 + g2*2 + 1][jl] << 16);
            unsigned short* dst = w1t + (size_t)(j0 + jl)*128 + chunk*32 + h*16;
            *(uint4*)dst       = make_uint4(words[0], words[1], words[2], words[3]);
            *(uint4*)(dst + 8) = make_uint4(words[4], words[5], words[6], words[7]);
            __syncthreads();
        }
    } else {
        // ---- prep: thread-per-row. 4 waves x 64 rows. ----
        float* xs = (float*)smem;                 // [wv][64 rows][64 cols], XOR-swizzled
        int wv = t >> 6, lane = t & 63;
        int rbase = (b - 264)*256 + wv*64;
        // stage x rows (coalesced), swizzle col' = col ^ (row & 31)
        for (int i = 0; i < 64; ++i)
            xs[wv*4096 + i*64 + (lane ^ (i & 31))] = x[(size_t)(rbase + i)*64 + lane];
        __syncthreads();
        int row = rbase + lane;
        float xr[64];
        #pragma unroll
        for (int c = 0; c < 64; ++c)
            xr[c] = xs[wv*4096 + lane*64 + (c ^ (lane & 31))];

        float mu = 0.f;
        #pragma unroll
        for (int u = 0; u < 16; ++u) mu += xr[u];
        mu *= (1.f/16.f);
        float var = 0.f;
        #pragma unroll
        for (int u = 0; u < 16; ++u){ float d = xr[u]-mu; var += d*d; }
        var *= (1.f/16.f);
        float inv = rsqrtf(var + EPS);
        float lnf[16];
        #pragma unroll
        for (int u = 0; u < 16; ++u) lnf[u] = (xr[u]-mu)*inv*lng[u] + lnb[u];

        // h for 64 k (w1 reads are lane-uniform -> scalar broadcast), coalesced Ht
        for (int k = 0; k < 64; ++k){
            float hk = 0.f;
            #pragma unroll
            for (int u = 0; u < 16; ++u) hk += lnf[u] * we_w1[u*64 + k];
            hk = hk / (1.f + expf(-hk));
            Ht[(size_t)k*N + row] = hk;
        }
        Ht[(size_t)64*N + row] = 1.f;

        // Q2 frag-major [rb][ps][quad][r64][8] bf16, coalesced uint4 stores
        int rb = rbase >> 6;
        #pragma unroll
        for (int ps = 0; ps < 16; ++ps){
            #pragma unroll
            for (int quad = 0; quad < 4; ++quad){
                union { unsigned short qs[8]; uint4 v; } qu;
                #pragma unroll
                for (int j = 0; j < 8; ++j){
                    int p = ps*32 + quad*8 + j;
                    float q;
                    if (p < 256){
                        int u = p >> 4, v = p & 15;
                        q = PATH_COEFF * xr[u] * xr[v];
                    } else {
                        int pp = p - 256;
                        int u = pp >> 4, v = pp & 15;
                        q = (PATH_COEFF * CG110) * (xr[16+u*3]*xr[16+v*3]
                           + xr[17+u*3]*xr[17+v*3] + xr[18+u*3]*xr[18+v*3]);
                    }
                    qu.qs[j] = f2bf(q);
                }
                *(uint4*)(Q2 + (((size_t)(rb*16 + ps)*4 + quad)*64 + lane)*8) = qu.v;
            }
        }
    }
}

// ---------------------------------------------------------------------------
// K1: partial[c][n][w] (fp16) = sum_{k in {2c,2c+1}} H[n,k]*(sum_p Q[n,p]V[k,p,w])
// 2-k chunks: A-frags loaded once per ps serve both k's. Grid 16 mb x 33 c,
// 256 thr = 4 waves (2x2), block tile 128 rows x 128 w, wave tile 64x64.
// ---------------------------------------------------------------------------
__global__ __launch_bounds__(256, 2)
void k_main(const unsigned short* __restrict__ Q2, const unsigned short* __restrict__ Vt2,
            const float* __restrict__ Ht, unsigned short* __restrict__ partial, int N)
{
    int tid  = threadIdx.x;
    int lane = tid & 63, wv = tid >> 6;
    int r2 = wv >> 1, c2 = wv & 1;
    int quad = lane >> 4, l16 = lane & 15;
    int mb = blockIdx.x / 33, c = blockIdx.x % 33;
    int k0 = c*2;
    bool two = (c < 32);
    int rowbase = mb*128 + r2*64;
    int rb = rowbase >> 6;
    int wbase = c2*64;

    const unsigned short* aroot = Q2  + (size_t)rb*32768 + quad*512  + l16*8;
    const unsigned short* b0r   = Vt2 + (size_t)k0*65536 + quad*1024 + (wbase + l16)*8;
    const unsigned short* b1r   = b0r + 65536;

    v4f t0[4][4], t1[4][4];
    #pragma unroll
    for (int m=0;m<4;++m)
      #pragma unroll
      for (int n=0;n<4;++n)
        #pragma unroll
        for (int r=0;r<4;++r){ t0[m][n][r] = 0.f; t1[m][n][r] = 0.f; }

    #pragma unroll 4
    for (int ps = 0; ps < 16; ++ps){
        const unsigned short* ap = aroot + ps*2048;
        v8bf a[4];
        #pragma unroll
        for (int m=0;m<4;++m) a[m] = *(const v8bf*)(ap + m*128);
        {
            const unsigned short* bp = b0r + ps*4096;
            v8bf bb[4];
            #pragma unroll
            for (int n=0;n<4;++n) bb[n] = *(const v8bf*)(bp + n*128);
            #pragma unroll
            for (int m=0;m<4;++m)
              #pragma unroll
              for (int n=0;n<4;++n)
                t0[m][n] = __builtin_amdgcn_mfma_f32_16x16x32_bf16(a[m], bb[n], t0[m][n], 0, 0, 0);
        }
        if (two){
            const unsigned short* bp = b1r + ps*4096;
            v8bf bb[4];
            #pragma unroll
            for (int n=0;n<4;++n) bb[n] = *(const v8bf*)(bp + n*128);
            #pragma unroll
            for (int m=0;m<4;++m)
              #pragma unroll
              for (int n=0;n<4;++n)
                t1[m][n] = __builtin_amdgcn_mfma_f32_16x16x32_bf16(a[m], bb[n], t1[m][n], 0, 0, 0);
        }
    }

    const float* hp0 = Ht + (size_t)k0*N + rowbase + quad*4;
    unsigned short* pp = partial + (size_t)c*N*128 + ((size_t)rowbase + quad*4)*128 + wbase + l16;
    #pragma unroll
    for (int m=0;m<4;++m){
        v4f hv0 = *(const v4f*)(hp0 + m*16);
        v4f hv1;
        if (two) hv1 = *(const v4f*)(hp0 + N + m*16);
        else { hv1[0]=hv1[1]=hv1[2]=hv1[3]=0.f; }
        #pragma unroll
        for (int n=0;n<4;++n)
          #pragma unroll
          for (int r=0;r<4;++r)
            pp[(size_t)(m*16 + r)*128 + n*16] = f2h(hv0[r]*t0[m][n][r] + hv1[r]*t1[m][n][r]);
    }
}

// ---------------------------------------------------------------------------
// K2: reduce 33 fp16 slices + LayerNorm(128) -> lnf bf16[row][128]
// block = 128 thr = one row (2 waves).
// ---------------------------------------------------------------------------
__global__ __launch_bounds__(128)
void k_red(const unsigned short* __restrict__ partial, const float* __restrict__ g,
           const float* __restrict__ b, unsigned short* __restrict__ lnf, int N)
{
    int row = blockIdx.x, t = threadIdx.x;
    const unsigned short* p0 = partial + (size_t)row*128 + t;
    float s = 0.f;
    #pragma unroll
    for (int sl = 0; sl < 33; ++sl) s += h2f(p0[(size_t)sl*N*128]);
    float a = s, q = s*s;
    #pragma unroll
    for (int off = 32; off > 0; off >>= 1){
        a += __shfl_down(a, off, 64);
        q += __shfl_down(q, off, 64);
    }
    __shared__ float red[4];
    int wv = t >> 6;
    if ((t & 63) == 0){ red[wv*2] = a; red[wv*2+1] = q; }
    __syncthreads();
    float sum = red[0] + red[2], sumsq = red[1] + red[3];
    float mu  = sum * (1.f/128.f);
    float var = sumsq * (1.f/128.f) - mu*mu;
    float inv = rsqrtf(var + EPS);
    lnf[(size_t)row*128 + t] = f2bf((s - mu)*inv*g[t] + b[t]);
}

// ---------------------------------------------------------------------------
// K3: out[n] = silu(lnf @ om_w1) @ om_w2 + om_b2. Grid 32 blocks x 64 rows,
// 256 thr = 4 waves, wave wv owns j in [wv*128, wv*128+128): 4x8 MFMA tiles.
// Cross-wave LDS reduce, direct store (no atomics, no memset).
// ---------------------------------------------------------------------------
__global__ __launch_bounds__(256)
void k_mlp2(const unsigned short* __restrict__ lnf, const unsigned short* __restrict__ w1t,
            const float* __restrict__ w2, const float* __restrict__ b2,
            float* __restrict__ out, int N)
{
    __shared__ float red2[4][64];
    int tid = threadIdx.x, lane = tid & 63, wv = tid >> 6;
    int quad = lane >> 4, l16 = lane & 15;
    int rowbase = blockIdx.x * 64;
    int jbase = wv * 128;

    v4f acc[4][8];
    #pragma unroll
    for (int m=0;m<4;++m)
      #pragma unroll
      for (int n=0;n<8;++n)
        #pragma unroll
        for (int r=0;r<4;++r) acc[m][n][r] = 0.f;

    #pragma unroll
    for (int ps = 0; ps < 4; ++ps){
        v8bf a[4], bb[8];
        #pragma unroll
        for (int m=0;m<4;++m)
            a[m]  = *(const v8bf*)(lnf + (size_t)(rowbase + m*16 + l16)*128 + ps*32 + quad*8);
        #pragma unroll
        for (int n=0;n<8;++n)
            bb[n] = *(const v8bf*)(w1t + (size_t)(jbase + n*16 + l16)*128 + ps*32 + quad*8);
        #pragma unroll
        for (int m=0;m<4;++m)
          #pragma unroll
          for (int n=0;n<8;++n)
            acc[m][n] = __builtin_amdgcn_mfma_f32_16x16x32_bf16(a[m], bb[n], acc[m][n], 0, 0, 0);
    }

    float w2v[8];
    #pragma unroll
    for (int n=0;n<8;++n) w2v[n] = w2[jbase + n*16 + l16];

    #pragma unroll
    for (int m=0;m<4;++m){
        #pragma unroll
        for (int r=0;r<4;++r){
            float s = 0.f;
            #pragma unroll
            for (int n=0;n<8;++n){
                float v = acc[m][n][r];
                s += (v / (1.f + expf(-v))) * w2v[n];
            }
            #pragma unroll
            for (int off=8; off>0; off>>=1) s += __shfl_xor(s, off, 16);
            if (l16 == 0) red2[wv][m*16 + quad*4 + r] = s;
        }
    }
    __syncthreads();
    if (tid < 64)
        out[rowbase + tid] = red2[0][tid] + red2[1][tid] + red2[2][tid] + red2[3][tid] + b2[0];
}

// ---------------------------------------------------------------------------
extern "C" void kernel_launch(void* const* d_in, const int* in_sizes, int n_in,
                              void* d_out, int out_size, void* d_ws, size_t ws_size,
                              hipStream_t stream)
{
    const float* x     = (const float*)d_in[0];
    const float* we_g  = (const float*)d_in[1];
    const float* we_b  = (const float*)d_in[2];
    const float* we_w1 = (const float*)d_in[3];
    const float* we_w2 = (const float*)d_in[4];
    const float* we_b2 = (const float*)d_in[5];
    const float* om_g  = (const float*)d_in[6];
    const float* om_b  = (const float*)d_in[7];
    const float* om_w1 = (const float*)d_in[8];
    const float* om_w2 = (const float*)d_in[9];
    const float* om_b2 = (const float*)d_in[10];

    int N  = in_sizes[0] / 64;     // 2048

    char* ws = (char*)d_ws;
    size_t offV = 0;
    size_t szV  = (size_t)65*16*4*128*8*2;       // 8,519,680
    size_t offQ = offV + szV;
    size_t szQ  = (size_t)N*512*2;               // 2 MB
    size_t offH = offQ + szQ;
    size_t szH  = (size_t)65*N*4;
    size_t offP = offH + szH;
    size_t szP  = (size_t)33*N*128*2;            // 17.3 MB fp16
    size_t offL = offP + szP;
    size_t szL  = (size_t)N*128*2;
    size_t offW = offL + szL;                    // +128 KB

    unsigned short* Vt2 = (unsigned short*)(ws + offV);
    unsigned short* Q2  = (unsigned short*)(ws + offQ);
    float* Ht           = (float*)(ws + offH);
    unsigned short* Par = (unsigned short*)(ws + offP);
    unsigned short* Lnf = (unsigned short*)(ws + offL);
    unsigned short* W1t = (unsigned short*)(ws + offW);
    float* out = (float*)d_out;

    hipLaunchKernelGGL(k_mega, dim3(272),       dim3(256), 0, stream,
                       we_w2, we_b2, Vt2, om_w1, W1t, x, we_g, we_b, we_w1, Q2, Ht, N);
    hipLaunchKernelGGL(k_main, dim3(16*33),     dim3(256), 0, stream, Q2, Vt2, Ht, Par, N);
    hipLaunchKernelGGL(k_red,  dim3(N),         dim3(128), 0, stream, Par, om_g, om_b, Lnf, N);
    hipLaunchKernelGGL(k_mlp2, dim3(N/64),      dim3(256), 0, stream, Lnf, W1t, om_w2, om_b2, out, N);
}

// Round 4
// 161.981 us; speedup vs baseline: 1.0078x; 1.0078x over previous
//
#include <hip/hip_runtime.h>
#include <hip/hip_bf16.h>
#include <cstdint>

#define EPS 1e-5f
#define PATH_COEFF 0.04419417382415922f   // 1/sqrt(512)
#define CG110     0.5773502691896258f     // 1/sqrt(3)

typedef __bf16 v8bf __attribute__((ext_vector_type(8)));
typedef float  v4f  __attribute__((ext_vector_type(4)));

static __device__ __forceinline__ unsigned short f2bf(float x){
    unsigned int u = __builtin_bit_cast(unsigned int, x);
    u += 0x7fffu + ((u >> 16) & 1u);      // RNE
    return (unsigned short)(u >> 16);
}
static __device__ __forceinline__ unsigned short f2h(float x){
    return __builtin_bit_cast(unsigned short, (_Float16)x);
}
static __device__ __forceinline__ float h2f(unsigned short b){
    return (float)__builtin_bit_cast(_Float16, b);
}

// ---------------------------------------------------------------------------
// K0 mega-kernel: blocks [0,260) convert we_w2/we_b2 -> Vt2 frag-major,
// blocks [260,264) transpose om_w1 -> w1t bf16, blocks [264,272) per-row prep.
// ---------------------------------------------------------------------------
__global__ __launch_bounds__(256)
void k_mega(const float* __restrict__ w2, const float* __restrict__ b2,
            unsigned short* __restrict__ Vt2,
            const float* __restrict__ om_w1, unsigned short* __restrict__ w1t,
            const float* __restrict__ x, const float* __restrict__ lng,
            const float* __restrict__ lnb, const float* __restrict__ we_w1,
            unsigned short* __restrict__ Q2, float* __restrict__ Ht, int N)
{
    __shared__ __align__(16) char smem[65536];
    int b = blockIdx.x;
    int t = threadIdx.x;

    if (b < 260){
        // ---- convV: Vt2[k][ps16][quad4][w128][8p] bf16 ----
        unsigned short (*tile)[128] = (unsigned short (*)[128])smem;
        int k    = b >> 2;
        int slab = b & 3;
        const float* srcbase = (k < 64) ? (w2 + (size_t)k * 65536) : b2;
        for (int chunk = 0; chunk < 4; ++chunk){
            int pbase = slab*128 + chunk*32;
            #pragma unroll
            for (int i = 0; i < 4; ++i){
                int g = t + 256*i;
                int ploc = g >> 5, c4 = g & 31;
                const float4 v = *(const float4*)(srcbase + (size_t)(pbase + ploc)*128 + c4*4);
                unsigned int w0 = (unsigned)f2bf(v.x) | ((unsigned)f2bf(v.y) << 16);
                unsigned int w1 = (unsigned)f2bf(v.z) | ((unsigned)f2bf(v.w) << 16);
                *(uint2*)&tile[ploc][c4*4] = make_uint2(w0, w1);
            }
            __syncthreads();
            int w = t & 127, h = t >> 7;
            int ps = slab*4 + chunk;
            unsigned int words[8];
            #pragma unroll
            for (int g2 = 0; g2 < 8; ++g2)
                words[g2] = (unsigned)tile[h*16 + g2*2][w] | ((unsigned)tile[h*16 + g2*2 + 1][w] << 16);
            unsigned short* dq0 = Vt2 + (((size_t)(k*16 + ps)*4 + 2*h    )*128 + w)*8;
            unsigned short* dq1 = Vt2 + (((size_t)(k*16 + ps)*4 + 2*h + 1)*128 + w)*8;
            *(uint4*)dq0 = make_uint4(words[0], words[1], words[2], words[3]);
            *(uint4*)dq1 = make_uint4(words[4], words[5], words[6], words[7]);
            __syncthreads();
        }
    } else if (b < 264){
        // ---- convW: w1t[j512][w128] bf16 = om_w1[w][j] ----
        unsigned short (*tile)[128] = (unsigned short (*)[128])smem;
        int j0 = (b - 260) * 128;
        for (int chunk = 0; chunk < 4; ++chunk){
            #pragma unroll
            for (int i = 0; i < 4; ++i){
                int g = t + 256*i;
                int wloc = g >> 5, c4 = g & 31;
                int w = chunk*32 + wloc;
                const float4 v = *(const float4*)(om_w1 + (size_t)w*512 + j0 + c4*4);
                unsigned int a = (unsigned)f2bf(v.x) | ((unsigned)f2bf(v.y) << 16);
                unsigned int bb = (unsigned)f2bf(v.z) | ((unsigned)f2bf(v.w) << 16);
                *(uint2*)&tile[wloc][c4*4] = make_uint2(a, bb);
            }
            __syncthreads();
            int jl = t & 127, h = t >> 7;
            unsigned int words[8];
            #pragma unroll
            for (int g2 = 0; g2 < 8; ++g2)
                words[g2] = (unsigned)tile[h*16 + g2*2][jl] | ((unsigned)tile[h*16 + g2*2 + 1][jl] << 16);
            unsigned short* dst = w1t + (size_t)(j0 + jl)*128 + chunk*32 + h*16;
            *(uint4*)dst       = make_uint4(words[0], words[1], words[2], words[3]);
            *(uint4*)(dst + 8) = make_uint4(words[4], words[5], words[6], words[7]);
            __syncthreads();
        }
    } else {
        // ---- prep: thread-per-row. 4 waves x 64 rows. ----
        float* xs = (float*)smem;
        int wv = t >> 6, lane = t & 63;
        int rbase = (b - 264)*256 + wv*64;
        for (int i = 0; i < 64; ++i)
            xs[wv*4096 + i*64 + (lane ^ (i & 31))] = x[(size_t)(rbase + i)*64 + lane];
        __syncthreads();
        int row = rbase + lane;
        float xr[64];
        #pragma unroll
        for (int c = 0; c < 64; ++c)
            xr[c] = xs[wv*4096 + lane*64 + (c ^ (lane & 31))];

        float mu = 0.f;
        #pragma unroll
        for (int u = 0; u < 16; ++u) mu += xr[u];
        mu *= (1.f/16.f);
        float var = 0.f;
        #pragma unroll
        for (int u = 0; u < 16; ++u){ float d = xr[u]-mu; var += d*d; }
        var *= (1.f/16.f);
        float inv = rsqrtf(var + EPS);
        float lnf[16];
        #pragma unroll
        for (int u = 0; u < 16; ++u) lnf[u] = (xr[u]-mu)*inv*lng[u] + lnb[u];

        for (int k = 0; k < 64; ++k){
            float hk = 0.f;
            #pragma unroll
            for (int u = 0; u < 16; ++u) hk += lnf[u] * we_w1[u*64 + k];
            hk = hk / (1.f + expf(-hk));
            Ht[(size_t)k*N + row] = hk;
        }
        Ht[(size_t)64*N + row] = 1.f;

        int rb = rbase >> 6;
        #pragma unroll
        for (int ps = 0; ps < 16; ++ps){
            #pragma unroll
            for (int quad = 0; quad < 4; ++quad){
                union { unsigned short qs[8]; uint4 v; } qu;
                #pragma unroll
                for (int j = 0; j < 8; ++j){
                    int p = ps*32 + quad*8 + j;
                    float q;
                    if (p < 256){
                        int u = p >> 4, v = p & 15;
                        q = PATH_COEFF * xr[u] * xr[v];
                    } else {
                        int pp = p - 256;
                        int u = pp >> 4, v = pp & 15;
                        q = (PATH_COEFF * CG110) * (xr[16+u*3]*xr[16+v*3]
                           + xr[17+u*3]*xr[17+v*3] + xr[18+u*3]*xr[18+v*3]);
                    }
                    qu.qs[j] = f2bf(q);
                }
                *(uint4*)(Q2 + (((size_t)(rb*16 + ps)*4 + quad)*64 + lane)*8) = qu.v;
            }
        }
    }
}

// ---------------------------------------------------------------------------
// K1: partial[k][n][w] (fp16) = H[n,k] * sum_p Q[n,p] V[k,p,w]
// One k per block, R2 structure (4 waves, 128x128 tile, lb(256,4), 50% occ).
// XCD-aware mapping: blockIdx = j*8 + g; XCD g owns k in [8g, 8g+8) so its
// ~1MB Vt2 slice stays L2-resident (per-XCD L2 = 4MiB < full Vt2 8.5MB).
// k=64 (bias) rides on g=0, j in [128,144).
// ---------------------------------------------------------------------------
__global__ __launch_bounds__(256, 4)
void k_main(const unsigned short* __restrict__ Q2, const unsigned short* __restrict__ Vt2,
            const float* __restrict__ Ht, unsigned short* __restrict__ partial, int N)
{
    int g = blockIdx.x & 7;
    int j = blockIdx.x >> 3;
    int kb, mb;
    if (j < 128){ mb = j >> 3; kb = g*8 + (j & 7); }
    else { if (g != 0) return; mb = j - 128; kb = 64; }

    int tid  = threadIdx.x;
    int lane = tid & 63, wv = tid >> 6;
    int r2 = wv >> 1, c2 = wv & 1;
    int quad = lane >> 4, l16 = lane & 15;
    int rowbase = mb*128 + r2*64;
    int rb = rowbase >> 6;
    int wbase = c2*64;

    const unsigned short* aroot = Q2  + (size_t)rb*32768 + quad*512  + l16*8;
    const unsigned short* broot = Vt2 + (size_t)kb*65536 + quad*1024 + (wbase + l16)*8;

    v4f acc[4][4];
    #pragma unroll
    for (int m=0;m<4;++m)
      #pragma unroll
      for (int n=0;n<4;++n)
        #pragma unroll
        for (int r=0;r<4;++r) acc[m][n][r] = 0.f;

    #pragma unroll 4
    for (int ps = 0; ps < 16; ++ps){
        const unsigned short* ap = aroot + ps*2048;
        const unsigned short* bp = broot + ps*4096;
        v8bf a[4], bb[4];
        #pragma unroll
        for (int m=0;m<4;++m) a[m]  = *(const v8bf*)(ap + m*128);
        #pragma unroll
        for (int n=0;n<4;++n) bb[n] = *(const v8bf*)(bp + n*128);
        #pragma unroll
        for (int m=0;m<4;++m)
          #pragma unroll
          for (int n=0;n<4;++n)
            acc[m][n] = __builtin_amdgcn_mfma_f32_16x16x32_bf16(a[m], bb[n], acc[m][n], 0, 0, 0);
    }

    const float* hp = Ht + (size_t)kb*N + rowbase + quad*4;
    unsigned short* pp = partial + (size_t)kb*N*128 + ((size_t)rowbase + quad*4)*128 + wbase + l16;
    #pragma unroll
    for (int m=0;m<4;++m){
        v4f hv = *(const v4f*)(hp + m*16);
        #pragma unroll
        for (int n=0;n<4;++n)
          #pragma unroll
          for (int r=0;r<4;++r)
            pp[(size_t)(m*16 + r)*128 + n*16] = f2h(hv[r]*acc[m][n][r]);
    }
}

// ---------------------------------------------------------------------------
// K2: reduce 65 fp16 slices + LayerNorm(128) -> lnf bf16[row][128]
// ---------------------------------------------------------------------------
__global__ __launch_bounds__(128)
void k_red(const unsigned short* __restrict__ partial, const float* __restrict__ g,
           const float* __restrict__ b, unsigned short* __restrict__ lnf, int N)
{
    int row = blockIdx.x, t = threadIdx.x;
    const unsigned short* p0 = partial + (size_t)row*128 + t;
    float s = 0.f;
    #pragma unroll
    for (int sl = 0; sl < 65; ++sl) s += h2f(p0[(size_t)sl*N*128]);
    float a = s, q = s*s;
    #pragma unroll
    for (int off = 32; off > 0; off >>= 1){
        a += __shfl_down(a, off, 64);
        q += __shfl_down(q, off, 64);
    }
    __shared__ float red[4];
    int wv = t >> 6;
    if ((t & 63) == 0){ red[wv*2] = a; red[wv*2+1] = q; }
    __syncthreads();
    float sum = red[0] + red[2], sumsq = red[1] + red[3];
    float mu  = sum * (1.f/128.f);
    float var = sumsq * (1.f/128.f) - mu*mu;
    float inv = rsqrtf(var + EPS);
    lnf[(size_t)row*128 + t] = f2bf((s - mu)*inv*g[t] + b[t]);
}

// ---------------------------------------------------------------------------
// K3: out[n] = silu(lnf @ om_w1) @ om_w2 + om_b2. 32 blocks x 64 rows,
// 4 waves, wave wv owns j-range [wv*128, +128): 4x8 MFMA tiles. LDS reduce.
// ---------------------------------------------------------------------------
__global__ __launch_bounds__(256)
void k_mlp2(const unsigned short* __restrict__ lnf, const unsigned short* __restrict__ w1t,
            const float* __restrict__ w2, const float* __restrict__ b2,
            float* __restrict__ out, int N)
{
    __shared__ float red2[4][64];
    int tid = threadIdx.x, lane = tid & 63, wv = tid >> 6;
    int quad = lane >> 4, l16 = lane & 15;
    int rowbase = blockIdx.x * 64;
    int jbase = wv * 128;

    v4f acc[4][8];
    #pragma unroll
    for (int m=0;m<4;++m)
      #pragma unroll
      for (int n=0;n<8;++n)
        #pragma unroll
        for (int r=0;r<4;++r) acc[m][n][r] = 0.f;

    #pragma unroll
    for (int ps = 0; ps < 4; ++ps){
        v8bf a[4], bb[8];
        #pragma unroll
        for (int m=0;m<4;++m)
            a[m]  = *(const v8bf*)(lnf + (size_t)(rowbase + m*16 + l16)*128 + ps*32 + quad*8);
        #pragma unroll
        for (int n=0;n<8;++n)
            bb[n] = *(const v8bf*)(w1t + (size_t)(jbase + n*16 + l16)*128 + ps*32 + quad*8);
        #pragma unroll
        for (int m=0;m<4;++m)
          #pragma unroll
          for (int n=0;n<8;++n)
            acc[m][n] = __builtin_amdgcn_mfma_f32_16x16x32_bf16(a[m], bb[n], acc[m][n], 0, 0, 0);
    }

    float w2v[8];
    #pragma unroll
    for (int n=0;n<8;++n) w2v[n] = w2[jbase + n*16 + l16];

    #pragma unroll
    for (int m=0;m<4;++m){
        #pragma unroll
        for (int r=0;r<4;++r){
            float s = 0.f;
            #pragma unroll
            for (int n=0;n<8;++n){
                float v = acc[m][n][r];
                s += (v / (1.f + expf(-v))) * w2v[n];
            }
            #pragma unroll
            for (int off=8; off>0; off>>=1) s += __shfl_xor(s, off, 16);
            if (l16 == 0) red2[wv][m*16 + quad*4 + r] = s;
        }
    }
    __syncthreads();
    if (tid < 64)
        out[rowbase + tid] = red2[0][tid] + red2[1][tid] + red2[2][tid] + red2[3][tid] + b2[0];
}

// ---------------------------------------------------------------------------
extern "C" void kernel_launch(void* const* d_in, const int* in_sizes, int n_in,
                              void* d_out, int out_size, void* d_ws, size_t ws_size,
                              hipStream_t stream)
{
    const float* x     = (const float*)d_in[0];
    const float* we_g  = (const float*)d_in[1];
    const float* we_b  = (const float*)d_in[2];
    const float* we_w1 = (const float*)d_in[3];
    const float* we_w2 = (const float*)d_in[4];
    const float* we_b2 = (const float*)d_in[5];
    const float* om_g  = (const float*)d_in[6];
    const float* om_b  = (const float*)d_in[7];
    const float* om_w1 = (const float*)d_in[8];
    const float* om_w2 = (const float*)d_in[9];
    const float* om_b2 = (const float*)d_in[10];

    int N  = in_sizes[0] / 64;     // 2048

    char* ws = (char*)d_ws;
    size_t offV = 0;
    size_t szV  = (size_t)65*16*4*128*8*2;       // 8,519,680
    size_t offQ = offV + szV;
    size_t szQ  = (size_t)N*512*2;               // 2 MB
    size_t offH = offQ + szQ;
    size_t szH  = (size_t)65*N*4;
    size_t offP = offH + szH;
    size_t szP  = (size_t)65*N*128*2;            // 34 MB fp16
    size_t offL = offP + szP;
    size_t szL  = (size_t)N*128*2;
    size_t offW = offL + szL;                    // +128 KB

    unsigned short* Vt2 = (unsigned short*)(ws + offV);
    unsigned short* Q2  = (unsigned short*)(ws + offQ);
    float* Ht           = (float*)(ws + offH);
    unsigned short* Par = (unsigned short*)(ws + offP);
    unsigned short* Lnf = (unsigned short*)(ws + offL);
    unsigned short* W1t = (unsigned short*)(ws + offW);
    float* out = (float*)d_out;

    hipLaunchKernelGGL(k_mega, dim3(272),   dim3(256), 0, stream,
                       we_w2, we_b2, Vt2, om_w1, W1t, x, we_g, we_b, we_w1, Q2, Ht, N);
    hipLaunchKernelGGL(k_main, dim3(144*8), dim3(256), 0, stream, Q2, Vt2, Ht, Par, N);
    hipLaunchKernelGGL(k_red,  dim3(N),     dim3(128), 0, stream, Par, om_g, om_b, Lnf, N);
    hipLaunchKernelGGL(k_mlp2, dim3(N/64),  dim3(256), 0, stream, Lnf, W1t, om_w2, om_b2, out, N);
}

// Round 5
// 145.790 us; speedup vs baseline: 1.1197x; 1.1111x over previous
//
#include <hip/hip_runtime.h>
#include <hip/hip_bf16.h>
#include <cstdint>

#define EPS 1e-5f
#define PATH_COEFF 0.04419417382415922f   // 1/sqrt(512)
#define CG110     0.5773502691896258f     // 1/sqrt(3)

typedef __bf16 v8bf __attribute__((ext_vector_type(8)));
typedef float  v4f  __attribute__((ext_vector_type(4)));
typedef _Float16 v4h __attribute__((ext_vector_type(4)));

static __device__ __forceinline__ unsigned short f2bf(float x){
    unsigned int u = __builtin_bit_cast(unsigned int, x);
    u += 0x7fffu + ((u >> 16) & 1u);      // RNE
    return (unsigned short)(u >> 16);
}
static __device__ __forceinline__ unsigned short f2h(float x){
    return __builtin_bit_cast(unsigned short, (_Float16)x);
}

// ---------------------------------------------------------------------------
// K0: fused prep. blocks [0,260): we_w2/we_b2 -> Vt2 frag-major (8KB LDS);
// [260,264): om_w1 -> w1t bf16 transpose; [264,776): per-row prep, wave/row.
// ---------------------------------------------------------------------------
__global__ __launch_bounds__(256)
void k_pre(const float* __restrict__ w2, const float* __restrict__ b2,
           unsigned short* __restrict__ Vt2,
           const float* __restrict__ om_w1, unsigned short* __restrict__ w1t,
           const float* __restrict__ x, const float* __restrict__ lng,
           const float* __restrict__ lnb, const float* __restrict__ we_w1,
           unsigned short* __restrict__ Q2, float* __restrict__ Ht, int N)
{
    __shared__ __align__(16) unsigned short tile[32][128];   // 8 KB
    int b = blockIdx.x;
    int t = threadIdx.x;

    if (b < 260){
        // ---- convV: Vt2[k][ps16][quad4][w128][8p] bf16 ----
        int k    = b >> 2;
        int slab = b & 3;
        const float* srcbase = (k < 64) ? (w2 + (size_t)k * 65536) : b2;
        for (int chunk = 0; chunk < 4; ++chunk){
            int pbase = slab*128 + chunk*32;
            #pragma unroll
            for (int i = 0; i < 4; ++i){
                int g = t + 256*i;
                int ploc = g >> 5, c4 = g & 31;
                const float4 v = *(const float4*)(srcbase + (size_t)(pbase + ploc)*128 + c4*4);
                unsigned int w0 = (unsigned)f2bf(v.x) | ((unsigned)f2bf(v.y) << 16);
                unsigned int w1 = (unsigned)f2bf(v.z) | ((unsigned)f2bf(v.w) << 16);
                *(uint2*)&tile[ploc][c4*4] = make_uint2(w0, w1);
            }
            __syncthreads();
            int w = t & 127, h = t >> 7;
            int ps = slab*4 + chunk;
            unsigned int words[8];
            #pragma unroll
            for (int g2 = 0; g2 < 8; ++g2)
                words[g2] = (unsigned)tile[h*16 + g2*2][w] | ((unsigned)tile[h*16 + g2*2 + 1][w] << 16);
            unsigned short* dq0 = Vt2 + (((size_t)(k*16 + ps)*4 + 2*h    )*128 + w)*8;
            unsigned short* dq1 = Vt2 + (((size_t)(k*16 + ps)*4 + 2*h + 1)*128 + w)*8;
            *(uint4*)dq0 = make_uint4(words[0], words[1], words[2], words[3]);
            *(uint4*)dq1 = make_uint4(words[4], words[5], words[6], words[7]);
            __syncthreads();
        }
    } else if (b < 264){
        // ---- convW: w1t[j512][w128] bf16 = om_w1[w][j] ----
        int j0 = (b - 260) * 128;
        for (int chunk = 0; chunk < 4; ++chunk){
            #pragma unroll
            for (int i = 0; i < 4; ++i){
                int g = t + 256*i;
                int wloc = g >> 5, c4 = g & 31;
                int w = chunk*32 + wloc;
                const float4 v = *(const float4*)(om_w1 + (size_t)w*512 + j0 + c4*4);
                unsigned int a = (unsigned)f2bf(v.x) | ((unsigned)f2bf(v.y) << 16);
                unsigned int bb = (unsigned)f2bf(v.z) | ((unsigned)f2bf(v.w) << 16);
                *(uint2*)&tile[wloc][c4*4] = make_uint2(a, bb);
            }
            __syncthreads();
            int jl = t & 127, h = t >> 7;
            unsigned int words[8];
            #pragma unroll
            for (int g2 = 0; g2 < 8; ++g2)
                words[g2] = (unsigned)tile[h*16 + g2*2][jl] | ((unsigned)tile[h*16 + g2*2 + 1][jl] << 16);
            unsigned short* dst = w1t + (size_t)(j0 + jl)*128 + chunk*32 + h*16;
            *(uint4*)dst       = make_uint4(words[0], words[1], words[2], words[3]);
            *(uint4*)(dst + 8) = make_uint4(words[4], words[5], words[6], words[7]);
            __syncthreads();
        }
    } else {
        // ---- prep: wave per row, 4 rows/block (R2 shape, no LDS) ----
        int wv = t >> 6, lane = t & 63;
        int row = (b - 264)*4 + wv;
        const float* xr = x + (size_t)row * 64;
        float f[16]; float mu = 0.f;
        #pragma unroll
        for (int u = 0; u < 16; ++u){ f[u] = xr[u]; mu += f[u]; }
        mu *= (1.f/16.f);
        float var = 0.f;
        #pragma unroll
        for (int u = 0; u < 16; ++u){ float d = f[u] - mu; var += d*d; }
        var *= (1.f/16.f);
        float inv = rsqrtf(var + EPS);
        float lnf[16];
        #pragma unroll
        for (int u = 0; u < 16; ++u) lnf[u] = (f[u]-mu)*inv*lng[u] + lnb[u];
        float h1 = 0.f;
        #pragma unroll
        for (int u = 0; u < 16; ++u) h1 += lnf[u] * we_w1[u*64 + lane];
        float h = h1 / (1.f + expf(-h1));
        Ht[(size_t)lane * N + row] = h;
        if (lane == 0) Ht[(size_t)64 * N + row] = 1.f;

        union { unsigned short qs[8]; uint4 v; } qu;
        #pragma unroll
        for (int j = 0; j < 8; ++j){
            int p = lane*8 + j;
            float q;
            if (p < 256){
                int u = p >> 4, v = p & 15;
                q = PATH_COEFF * f[u] * f[v];
            } else {
                int pp = p - 256;
                int u = pp >> 4, v = pp & 15;
                const float* ya = xr + 16 + u*3;
                const float* yb = xr + 16 + v*3;
                q = (PATH_COEFF * CG110) * (ya[0]*yb[0] + ya[1]*yb[1] + ya[2]*yb[2]);
            }
            qu.qs[j] = f2bf(q);
        }
        int rb = row >> 6, r64 = row & 63;
        int ps = lane >> 2, quad4 = lane & 3;
        *(uint4*)(Q2 + (((size_t)(rb*16 + ps)*4 + quad4)*64 + r64)*8) = qu.v;
    }
}

// ---------------------------------------------------------------------------
// K1: partial[k][n][w] (fp16) = H[n,k] * sum_p Q[n,p] V[k,p,w]
// One k per block, 4 waves, 128x128 tile, lb(256,4). XCD swizzle: blockIdx =
// j*8+g, XCD g owns k in [8g,8g+8); k=64 rides g=0, j in [128,144).
// Epilogue: per-wave LDS transpose -> dense 128B row stores (no write amp).
// ---------------------------------------------------------------------------
__global__ __launch_bounds__(256, 4)
void k_main(const unsigned short* __restrict__ Q2, const unsigned short* __restrict__ Vt2,
            const float* __restrict__ Ht, unsigned short* __restrict__ partial, int N)
{
    __shared__ __align__(16) unsigned short stile[4][64*72];   // 36.9 KB
    int g = blockIdx.x & 7;
    int j = blockIdx.x >> 3;
    int kb, mb;
    if (j < 128){ mb = j >> 3; kb = g*8 + (j & 7); }
    else { if (g != 0) return; mb = j - 128; kb = 64; }

    int tid  = threadIdx.x;
    int lane = tid & 63, wv = tid >> 6;
    int r2 = wv >> 1, c2 = wv & 1;
    int quad = lane >> 4, l16 = lane & 15;
    int rowbase = mb*128 + r2*64;
    int rb = rowbase >> 6;
    int wbase = c2*64;

    const unsigned short* aroot = Q2  + (size_t)rb*32768 + quad*512  + l16*8;
    const unsigned short* broot = Vt2 + (size_t)kb*65536 + quad*1024 + (wbase + l16)*8;

    v4f acc[4][4];
    #pragma unroll
    for (int m=0;m<4;++m)
      #pragma unroll
      for (int n=0;n<4;++n)
        #pragma unroll
        for (int r=0;r<4;++r) acc[m][n][r] = 0.f;

    #pragma unroll 4
    for (int ps = 0; ps < 16; ++ps){
        const unsigned short* ap = aroot + ps*2048;
        const unsigned short* bp = broot + ps*4096;
        v8bf a[4], bb[4];
        #pragma unroll
        for (int m=0;m<4;++m) a[m]  = *(const v8bf*)(ap + m*128);
        #pragma unroll
        for (int n=0;n<4;++n) bb[n] = *(const v8bf*)(bp + n*128);
        #pragma unroll
        for (int m=0;m<4;++m)
          #pragma unroll
          for (int n=0;n<4;++n)
            acc[m][n] = __builtin_amdgcn_mfma_f32_16x16x32_bf16(a[m], bb[n], acc[m][n], 0, 0, 0);
    }

    // fold H and stage fp16 tile in wave-private LDS (no barrier needed)
    const float* hp = Ht + (size_t)kb*N + rowbase + quad*4;
    unsigned short* my = stile[wv];
    #pragma unroll
    for (int m=0;m<4;++m){
        v4f hv = *(const v4f*)(hp + m*16);
        #pragma unroll
        for (int n=0;n<4;++n)
          #pragma unroll
          for (int r=0;r<4;++r)
            my[(m*16 + quad*4 + r)*72 + n*16 + l16] = f2h(hv[r]*acc[m][n][r]);
    }
    // dense stores: 8 insts x (8 rows x 128B)
    unsigned short* gp = partial + (size_t)kb*N*128 + (size_t)rowbase*128 + wbase;
    #pragma unroll
    for (int i = 0; i < 8; ++i){
        int row = i*8 + (lane >> 3);
        int c16 = (lane & 7)*8;
        uint4 v = *(const uint4*)&my[row*72 + c16];
        *(uint4*)(gp + (size_t)row*128 + c16) = v;
    }
}

// ---------------------------------------------------------------------------
// K2: reduce 65 fp16 slices + LayerNorm(128) -> lnf bf16. 4 rows/block,
// 128 thr: thread owns (row = t>>5, w = (t&31)*4). Dense 8B loads.
// ---------------------------------------------------------------------------
__global__ __launch_bounds__(128)
void k_red(const unsigned short* __restrict__ partial, const float* __restrict__ g,
           const float* __restrict__ b, unsigned short* __restrict__ lnf, int N)
{
    int t = threadIdx.x;
    int row0 = blockIdx.x * 4;
    int rl = t >> 5, w = (t & 31)*4;
    int row = row0 + rl;

    const unsigned short* p0 = partial + (size_t)row*128 + w;
    float s0=0.f, s1=0.f, s2=0.f, s3=0.f;
    #pragma unroll
    for (int sl = 0; sl < 65; ++sl){
        v4h v = *(const v4h*)(p0 + (size_t)sl*N*128);
        s0 += (float)v[0]; s1 += (float)v[1]; s2 += (float)v[2]; s3 += (float)v[3];
    }
    float sum = s0+s1+s2+s3;
    float sq  = s0*s0+s1*s1+s2*s2+s3*s3;
    #pragma unroll
    for (int off=16; off>0; off>>=1){
        sum += __shfl_xor(sum, off, 32);
        sq  += __shfl_xor(sq,  off, 32);
    }
    float mu  = sum * (1.f/128.f);
    float var = sq * (1.f/128.f) - mu*mu;
    float inv = rsqrtf(var + EPS);
    unsigned short o[4];
    o[0] = f2bf((s0-mu)*inv*g[w+0] + b[w+0]);
    o[1] = f2bf((s1-mu)*inv*g[w+1] + b[w+1]);
    o[2] = f2bf((s2-mu)*inv*g[w+2] + b[w+2]);
    o[3] = f2bf((s3-mu)*inv*g[w+3] + b[w+3]);
    *(uint2*)(lnf + (size_t)row*128 + w) = *(uint2*)o;
}

// ---------------------------------------------------------------------------
// K3: out[n] = silu(lnf @ om_w1) @ om_w2 + om_b2. 32 blocks x 64 rows,
// 4 waves, wave wv owns j-range [wv*128, +128): 4x8 MFMA tiles. LDS reduce.
// ---------------------------------------------------------------------------
__global__ __launch_bounds__(256)
void k_mlp2(const unsigned short* __restrict__ lnf, const unsigned short* __restrict__ w1t,
            const float* __restrict__ w2, const float* __restrict__ b2,
            float* __restrict__ out, int N)
{
    __shared__ float red2[4][64];
    int tid = threadIdx.x, lane = tid & 63, wv = tid >> 6;
    int quad = lane >> 4, l16 = lane & 15;
    int rowbase = blockIdx.x * 64;
    int jbase = wv * 128;

    v4f acc[4][8];
    #pragma unroll
    for (int m=0;m<4;++m)
      #pragma unroll
      for (int n=0;n<8;++n)
        #pragma unroll
        for (int r=0;r<4;++r) acc[m][n][r] = 0.f;

    #pragma unroll
    for (int ps = 0; ps < 4; ++ps){
        v8bf a[4], bb[8];
        #pragma unroll
        for (int m=0;m<4;++m)
            a[m]  = *(const v8bf*)(lnf + (size_t)(rowbase + m*16 + l16)*128 + ps*32 + quad*8);
        #pragma unroll
        for (int n=0;n<8;++n)
            bb[n] = *(const v8bf*)(w1t + (size_t)(jbase + n*16 + l16)*128 + ps*32 + quad*8);
        #pragma unroll
        for (int m=0;m<4;++m)
          #pragma unroll
          for (int n=0;n<8;++n)
            acc[m][n] = __builtin_amdgcn_mfma_f32_16x16x32_bf16(a[m], bb[n], acc[m][n], 0, 0, 0);
    }

    float w2v[8];
    #pragma unroll
    for (int n=0;n<8;++n) w2v[n] = w2[jbase + n*16 + l16];

    #pragma unroll
    for (int m=0;m<4;++m){
        #pragma unroll
        for (int r=0;r<4;++r){
            float s = 0.f;
            #pragma unroll
            for (int n=0;n<8;++n){
                float v = acc[m][n][r];
                s += (v / (1.f + expf(-v))) * w2v[n];
            }
            #pragma unroll
            for (int off=8; off>0; off>>=1) s += __shfl_xor(s, off, 16);
            if (l16 == 0) red2[wv][m*16 + quad*4 + r] = s;
        }
    }
    __syncthreads();
    if (tid < 64)
        out[rowbase + tid] = red2[0][tid] + red2[1][tid] + red2[2][tid] + red2[3][tid] + b2[0];
}

// ---------------------------------------------------------------------------
extern "C" void kernel_launch(void* const* d_in, const int* in_sizes, int n_in,
                              void* d_out, int out_size, void* d_ws, size_t ws_size,
                              hipStream_t stream)
{
    const float* x     = (const float*)d_in[0];
    const float* we_g  = (const float*)d_in[1];
    const float* we_b  = (const float*)d_in[2];
    const float* we_w1 = (const float*)d_in[3];
    const float* we_w2 = (const float*)d_in[4];
    const float* we_b2 = (const float*)d_in[5];
    const float* om_g  = (const float*)d_in[6];
    const float* om_b  = (const float*)d_in[7];
    const float* om_w1 = (const float*)d_in[8];
    const float* om_w2 = (const float*)d_in[9];
    const float* om_b2 = (const float*)d_in[10];

    int N  = in_sizes[0] / 64;     // 2048

    char* ws = (char*)d_ws;
    size_t offV = 0;
    size_t szV  = (size_t)65*16*4*128*8*2;       // 8,519,680
    size_t offQ = offV + szV;
    size_t szQ  = (size_t)N*512*2;               // 2 MB
    size_t offH = offQ + szQ;
    size_t szH  = (size_t)65*N*4;
    size_t offP = offH + szH;
    size_t szP  = (size_t)65*N*128*2;            // 34 MB fp16
    size_t offL = offP + szP;
    size_t szL  = (size_t)N*128*2;
    size_t offW = offL + szL;                    // +128 KB

    unsigned short* Vt2 = (unsigned short*)(ws + offV);
    unsigned short* Q2  = (unsigned short*)(ws + offQ);
    float* Ht           = (float*)(ws + offH);
    unsigned short* Par = (unsigned short*)(ws + offP);
    unsigned short* Lnf = (unsigned short*)(ws + offL);
    unsigned short* W1t = (unsigned short*)(ws + offW);
    float* out = (float*)d_out;

    hipLaunchKernelGGL(k_pre,  dim3(264 + N/4), dim3(256), 0, stream,
                       we_w2, we_b2, Vt2, om_w1, W1t, x, we_g, we_b, we_w1, Q2, Ht, N);
    hipLaunchKernelGGL(k_main, dim3(144*8),     dim3(256), 0, stream, Q2, Vt2, Ht, Par, N);
    hipLaunchKernelGGL(k_red,  dim3(N/4),       dim3(128), 0, stream, Par, om_g, om_b, Lnf, N);
    hipLaunchKernelGGL(k_mlp2, dim3(N/64),      dim3(256), 0, stream, Lnf, W1t, om_w2, om_b2, out, N);
}